// Round 11
// baseline (4013.244 us; speedup 1.0000x reference)
//
#include <hip/hip_runtime.h>
#include <hip/hip_bf16.h>

#define B_     32
#define NTOK   197
#define NPATCH 196
#define D_     768
#define H_     12
#define HD_    64
#define DEPTH_ 12
#define MLPD_  3072
#define TASKS_ 10
#define PL_    5
#define NPL_   5
#define SCALE_ 0.125f
#define ROWS   (B_*NTOK)   // 6304
#define PSZ    (ROWS*D_)   // 4,841,472 per fc2 partial

typedef unsigned short ushortT;
typedef __bf16 bf16x8 __attribute__((ext_vector_type(8)));
typedef float  f32x4  __attribute__((ext_vector_type(4)));
typedef unsigned int u32x4 __attribute__((ext_vector_type(4)));

union FragU { u32x4 u; bf16x8 b; };

// ---------- helpers ----------
__device__ inline unsigned int f2bf(float f){
  unsigned int u = __float_as_uint(f);
  return (u + 0x7fffu + ((u >> 16) & 1u)) >> 16;   // RNE to bf16
}
__device__ inline float bflo(unsigned int u){ return __uint_as_float(u << 16); }
__device__ inline float bfhi(unsigned int u){ return __uint_as_float(u & 0xffff0000u); }
__device__ inline float gelu_f(float x){ return 0.5f * x * (1.f + erff(x * 0.70710678118f)); }

__device__ inline void gload16(const void* g, void* l){
  __builtin_amdgcn_global_load_lds(
      (const __attribute__((address_space(1))) void*)(uintptr_t)g,
      (__attribute__((address_space(3))) void*)(uintptr_t)l,
      16, 0, 0);
}

#define DSREAD(dst, addr, OFFS) \
  asm volatile("ds_read_b128 %0, %1 offset:" OFFS : "=v"(dst) : "v"(addr))

// ---------- weight conversion fp32 -> bf16 ----------
__global__ __launch_bounds__(256) void convw4_kernel(const float* __restrict__ s0,
    const float* __restrict__ s1, const float* __restrict__ s2, const float* __restrict__ s3,
    ushortT* __restrict__ dst)
{
  int idx = blockIdx.x * 256 + threadIdx.x;
  int e = idx * 8;
  if (e >= 7077888) return;
  const float* s; int loc;
  if (e < 1769472)      { s = s0; loc = e; }
  else if (e < 2359296) { s = s1; loc = e - 1769472; }
  else if (e < 4718592) { s = s2; loc = e - 2359296; }
  else                  { s = s3; loc = e - 4718592; }
  float4 a = *(const float4*)(s + loc);
  float4 c = *(const float4*)(s + loc + 4);
  uint4 o;
  o.x = f2bf(a.x) | (f2bf(a.y) << 16);
  o.y = f2bf(a.z) | (f2bf(a.w) << 16);
  o.z = f2bf(c.x) | (f2bf(c.y) << 16);
  o.w = f2bf(c.z) | (f2bf(c.w) << 16);
  *(uint4*)(dst + e) = o;
}

__global__ __launch_bounds__(256) void convw1_kernel(const float* __restrict__ s,
    ushortT* __restrict__ dst, int n8)
{
  int idx = blockIdx.x * 256 + threadIdx.x;
  if (idx >= n8) return;
  int e = idx * 8;
  float4 a = *(const float4*)(s + e);
  float4 c = *(const float4*)(s + e + 4);
  uint4 o;
  o.x = f2bf(a.x) | (f2bf(a.y) << 16);
  o.y = f2bf(a.z) | (f2bf(a.w) << 16);
  o.z = f2bf(c.x) | (f2bf(c.y) << 16);
  o.w = f2bf(c.z) | (f2bf(c.w) << 16);
  *(uint4*)(dst + e) = o;
}

// ---------- im2col (bf16 out) ----------
__global__ __launch_bounds__(256) void im2col_kernel(const float* __restrict__ x,
                                                     ushortT* __restrict__ out)
{
  int idx = blockIdx.x * 256 + threadIdx.x;
  const int tot = B_ * NPATCH * D_;
  if (idx >= tot) return;
  int m = idx / D_, k = idx - m * D_;
  int b = m / NPATCH, p = m - b * NPATCH;
  int pr = p / 14, pc = p - pr * 14;
  int c = k >> 8, r = k & 255;
  int py = r >> 4, px = r & 15;
  float v = x[(((size_t)(b * 3 + c) * 224) + pr * 16 + py) * 224 + pc * 16 + px];
  out[idx] = (ushortT)f2bf(v);
}

// ---------- assemble h0 = [cls; patches+patch_b] + pos (fp32) ----------
__global__ __launch_bounds__(256) void assemble_kernel(const float* __restrict__ pe,
    const float* __restrict__ patch_b, const float* __restrict__ cls,
    const float* __restrict__ pos, float* __restrict__ h)
{
  int idx = blockIdx.x * 256 + threadIdx.x;
  const int tot = ROWS * D_;
  if (idx >= tot) return;
  int bn = idx / D_, d = idx - bn * D_;
  int b = bn / NTOK, n = bn - b * NTOK;
  float v;
  if (n == 0) v = cls[d];
  else        v = pe[((size_t)b * NPATCH + (n - 1)) * D_ + d] + patch_b[d];
  h[idx] = v + pos[(size_t)n * D_ + d];
}

// ---------- fc2 split-K reduce: h += p0+p1+p2 + bias ----------
__global__ __launch_bounds__(256) void reduce3_kernel(
    const ushortT* __restrict__ p, const float* __restrict__ bias,
    float* __restrict__ h)
{
  int idx = blockIdx.x * 256 + threadIdx.x;
  int e = idx * 8;
  int n = e % D_;
  uint4 a = *(const uint4*)(p + e);
  uint4 b = *(const uint4*)(p + PSZ + e);
  uint4 c = *(const uint4*)(p + 2 * PSZ + e);
  float4 h0 = *(const float4*)(h + e);
  float4 h1 = *(const float4*)(h + e + 4);
  float4 bb0 = *(const float4*)(bias + n);
  float4 bb1 = *(const float4*)(bias + n + 4);
  float r0 = h0.x + bb0.x + bflo(a.x) + bflo(b.x) + bflo(c.x);
  float r1 = h0.y + bb0.y + bfhi(a.x) + bfhi(b.x) + bfhi(c.x);
  float r2 = h0.z + bb0.z + bflo(a.y) + bflo(b.y) + bflo(c.y);
  float r3 = h0.w + bb0.w + bfhi(a.y) + bfhi(b.y) + bfhi(c.y);
  float r4 = h1.x + bb1.x + bflo(a.z) + bflo(b.z) + bflo(c.z);
  float r5 = h1.y + bb1.y + bfhi(a.z) + bfhi(b.z) + bfhi(c.z);
  float r6 = h1.z + bb1.z + bflo(a.w) + bflo(b.w) + bflo(c.w);
  float r7 = h1.w + bb1.w + bfhi(a.w) + bfhi(b.w) + bfhi(c.w);
  *(float4*)(h + e)     = (float4){r0, r1, r2, r3};
  *(float4*)(h + e + 4) = (float4){r4, r5, r6, r7};
}

// ---------- LayerNorm (one block per row), templated output ----------
template<int OUTBF>
__global__ __launch_bounds__(256) void ln_kernel(const float* __restrict__ x, size_t xstride,
    const float* __restrict__ w, const float* __restrict__ b,
    void* __restrict__ y, size_t ystride)
{
  const float* xr = x + (size_t)blockIdx.x * xstride;
  float vals[3];
  float s = 0.f, ss = 0.f;
  #pragma unroll
  for (int t = 0; t < 3; t++) {
    float v = xr[threadIdx.x + t * 256];
    vals[t] = v; s += v; ss += v * v;
  }
  #pragma unroll
  for (int off = 32; off >= 1; off >>= 1) {
    s  += __shfl_down(s, off);
    ss += __shfl_down(ss, off);
  }
  __shared__ float sm[4], ssm[4];
  int wid = threadIdx.x >> 6, lane = threadIdx.x & 63;
  if (lane == 0) { sm[wid] = s; ssm[wid] = ss; }
  __syncthreads();
  s  = sm[0] + sm[1] + sm[2] + sm[3];
  ss = ssm[0] + ssm[1] + ssm[2] + ssm[3];
  float mean = s * (1.f / D_);
  float var  = ss * (1.f / D_) - mean * mean;
  float inv  = rsqrtf(var + 1e-6f);
  #pragma unroll
  for (int t = 0; t < 3; t++) {
    int d = threadIdx.x + t * 256;
    float v = (vals[t] - mean) * inv * w[d] + b[d];
    if (OUTBF) ((ushortT*)y)[(size_t)blockIdx.x * ystride + d] = (ushortT)f2bf(v);
    else       ((float*)y)  [(size_t)blockIdx.x * ystride + d] = v;
  }
}

// ---------- narrow bf16 MFMA GEMM (round-9 best): 128x64, 2-buf vmcnt(3), 5 blk/CU ----------
template<int OUTBF, int ACT, int HASRES>
__global__ __launch_bounds__(256, 5) void gemm_mfma(
    const ushortT* __restrict__ A, const ushortT* __restrict__ W,
    const float* __restrict__ bias, const float* __restrict__ resid,
    void* __restrict__ Cout, int M, int N, int K, int LDA, int LDW)
{
  __shared__ ushortT lds[12288];   // 24 KB
  const int tid = threadIdx.x, lane = tid & 63, wid = tid >> 6;
  const int bm = blockIdx.y * 128, bn = blockIdx.x * 64;
  const int wm = (wid >> 1) * 64, wn = (wid & 1) * 32;
  const int kz = blockIdx.z;
  A += (size_t)kz * K; W += (size_t)kz * K;
  char* Cb = (char*)Cout + (size_t)kz * M * N * (OUTBF ? 2 : 4);

  const int srow = lane >> 2;
  const int scol = ((lane & 3) ^ ((lane >> 3) & 3)) * 8;
  int arow0 = bm + (2 * wid) * 16 + srow;     if (arow0 > M - 1) arow0 = M - 1;
  int arow1 = bm + (2 * wid + 1) * 16 + srow; if (arow1 > M - 1) arow1 = M - 1;
  const int wrow = bn + wid * 16 + srow;
  const ushortT* aP0 = A + (size_t)arow0 * LDA + scol;
  const ushortT* aP1 = A + (size_t)arow1 * LDA + scol;
  const ushortT* wP0 = W + (size_t)wrow * LDW + scol;
  ushortT* sA = lds + 2 * wid * 512;
  ushortT* sW = lds + 8192 + wid * 512;

  f32x4 acc[4][2];
  #pragma unroll
  for (int i = 0; i < 4; i++)
    #pragma unroll
    for (int j = 0; j < 2; j++)
      acc[i][j] = (f32x4){0.f, 0.f, 0.f, 0.f};

  const int rsel = lane & 15, kc = lane >> 4;
  const unsigned ldsbase = (unsigned)(size_t)&lds[0];
  const unsigned rowoff = (unsigned)(rsel * 64 + ((kc ^ ((rsel >> 1) & 3)) << 4));
  const unsigned aBase = ldsbase + (unsigned)(wm * 64) + rowoff;
  const unsigned bBase = ldsbase + 16384u + (unsigned)(wn * 64) + rowoff;

  const int nk = K >> 5;

  #pragma unroll
  for (int p = 0; p < 2; ++p) {
    const int off = p * 32;
    gload16(aP0 + off, sA + p * 4096); gload16(aP1 + off, sA + p * 4096 + 512);
    gload16(wP0 + off, sW + p * 2048);
  }

  for (int kt = 0; kt < nk; ++kt) {
    const int cb = kt & 1;
    asm volatile("s_waitcnt vmcnt(3)" ::: "memory");
    __builtin_amdgcn_sched_barrier(0);
    __builtin_amdgcn_s_barrier();

    const unsigned aAddr = aBase + (unsigned)cb * 8192u;
    const unsigned bAddr = bBase + (unsigned)cb * 4096u;
    FragU fa0, fa1, fa2, fa3, fb0, fb1;
    DSREAD(fa0.u, aAddr, "0");
    DSREAD(fa1.u, aAddr, "1024");
    DSREAD(fa2.u, aAddr, "2048");
    DSREAD(fa3.u, aAddr, "3072");
    DSREAD(fb0.u, bAddr, "0");
    DSREAD(fb1.u, bAddr, "1024");
    asm volatile("s_waitcnt lgkmcnt(0)" ::: "memory");
    __builtin_amdgcn_sched_barrier(0);
    __builtin_amdgcn_s_barrier();

    const int nt = kt + 2;
    const int off = (nt < nk) ? nt * 32 : 0;
    gload16(aP0 + off, sA + cb * 4096); gload16(aP1 + off, sA + cb * 4096 + 512);
    gload16(wP0 + off, sW + cb * 2048);

    acc[0][0] = __builtin_amdgcn_mfma_f32_16x16x32_bf16(fa0.b, fb0.b, acc[0][0], 0, 0, 0);
    acc[0][1] = __builtin_amdgcn_mfma_f32_16x16x32_bf16(fa0.b, fb1.b, acc[0][1], 0, 0, 0);
    acc[1][0] = __builtin_amdgcn_mfma_f32_16x16x32_bf16(fa1.b, fb0.b, acc[1][0], 0, 0, 0);
    acc[1][1] = __builtin_amdgcn_mfma_f32_16x16x32_bf16(fa1.b, fb1.b, acc[1][1], 0, 0, 0);
    acc[2][0] = __builtin_amdgcn_mfma_f32_16x16x32_bf16(fa2.b, fb0.b, acc[2][0], 0, 0, 0);
    acc[2][1] = __builtin_amdgcn_mfma_f32_16x16x32_bf16(fa2.b, fb1.b, acc[2][1], 0, 0, 0);
    acc[3][0] = __builtin_amdgcn_mfma_f32_16x16x32_bf16(fa3.b, fb0.b, acc[3][0], 0, 0, 0);
    acc[3][1] = __builtin_amdgcn_mfma_f32_16x16x32_bf16(fa3.b, fb1.b, acc[3][1], 0, 0, 0);
  }

  const int crow = (lane >> 4) * 4, ccol = lane & 15;
  #pragma unroll
  for (int i = 0; i < 4; i++) {
    #pragma unroll
    for (int r = 0; r < 4; r++) {
      int m = bm + wm + i * 16 + crow + r;
      if (m < M) {
        #pragma unroll
        for (int j = 0; j < 2; j++) {
          int n = bn + wn + j * 16 + ccol;
          float v = acc[i][j][r];
          if (bias) v += bias[n];
          if (ACT) v = gelu_f(v);
          if (HASRES) v += resid[(size_t)m * N + n];
          if (OUTBF) ((ushortT*)Cb)[(size_t)m * N + n] = (ushortT)f2bf(v);
          else       ((float*)Cb)  [(size_t)m * N + n] = v;
        }
      }
    }
  }
  asm volatile("s_waitcnt vmcnt(0)" ::: "memory");
}

// ---------- 256x256 8-wave phase-split GEMM (m201-family, BK=32, 3-buf, 1 barrier/K-tile) --
// 8 waves = 2m x 4n, per-wave 128x64 output (acc[8][4]); LDS 96KB = 3 K-tile bufs x (A 16KB
// + B 16KB). Per K-tile: vmcnt(4) (tile kt landed; kt+1 in flight) -> barrier (also proves
// buf rb free) -> ph0 {stage A of kt+2, ds_read B 4 + A-half0 4, lgkm, setprio, 16 MFMA}
// -> ph1 {stage B of kt+2, ds_read A-half1 4, lgkm, setprio, 16 MFMA}. N must be mult of 256.
template<int OUTBF, int ACT>
__global__ __launch_bounds__(512, 2) void gemm_wide(
    const ushortT* __restrict__ A, const ushortT* __restrict__ W,
    const float* __restrict__ bias,
    void* __restrict__ Cout, int M, int N, int K, int LDA, int LDW)
{
  __shared__ ushortT lds[49152];   // 96 KB: A bufs [3][8192] @0; B bufs [3][8192] @24576
  const int tid = threadIdx.x, lane = tid & 63, wid = tid >> 6;   // wid 0..7
  const int bm = blockIdx.y * 256, bn = blockIdx.x * 256;
  const int wm = (wid >> 2) * 128, wn = (wid & 3) * 64;
  const int kz = blockIdx.z;
  A += (size_t)kz * K; W += (size_t)kz * K;
  char* Cb = (char*)Cout + (size_t)kz * M * N * (OUTBF ? 2 : 4);

  // staging: wave w owns A chunks {2w,2w+1} and B chunks {2w,2w+1} (chunk = 16 rows x 32 k)
  const int srow = lane >> 2;
  const int scol = ((lane & 3) ^ ((lane >> 3) & 3)) * 8;
  int arow0 = bm + (2 * wid) * 16 + srow;     if (arow0 > M - 1) arow0 = M - 1;
  int arow1 = bm + (2 * wid + 1) * 16 + srow; if (arow1 > M - 1) arow1 = M - 1;
  const int wrow0 = bn + (2 * wid) * 16 + srow;
  const int wrow1 = bn + (2 * wid + 1) * 16 + srow;
  const ushortT* aP0 = A + (size_t)arow0 * LDA + scol;
  const ushortT* aP1 = A + (size_t)arow1 * LDA + scol;
  const ushortT* wP0 = W + (size_t)wrow0 * LDW + scol;
  const ushortT* wP1 = W + (size_t)wrow1 * LDW + scol;
  ushortT* sA = lds + 2 * wid * 512;             // + buf*8192 elems (+512 chunk1)
  ushortT* sW = lds + 24576 + 2 * wid * 512;     // + buf*8192 elems

  f32x4 acc[8][4];
  #pragma unroll
  for (int i = 0; i < 8; i++)
    #pragma unroll
    for (int j = 0; j < 4; j++)
      acc[i][j] = (f32x4){0.f, 0.f, 0.f, 0.f};

  // read addressing (bytes): row stride 64B; swizzled 16B slot kc ^ ((rsel>>1)&3)
  const int rsel = lane & 15, kc = lane >> 4;
  const unsigned ldsbase = (unsigned)(size_t)&lds[0];
  const unsigned rowoff = (unsigned)(rsel * 64 + ((kc ^ ((rsel >> 1) & 3)) << 4));
  const unsigned aBase = ldsbase + (unsigned)(wm * 64) + rowoff;
  const unsigned bBase = ldsbase + 49152u + (unsigned)(wn * 64) + rowoff;

  const int nk = K >> 5;

  // prologue: stage tiles 0,1 into bufs 0,1 (8 loads/wave in flight)
  #pragma unroll
  for (int p = 0; p < 2; ++p) {
    const int off = p * 32;
    gload16(aP0 + off, sA + p * 8192); gload16(aP1 + off, sA + p * 8192 + 512);
    gload16(wP0 + off, sW + p * 8192); gload16(wP1 + off, sW + p * 8192 + 512);
  }

  int cb = 0;          // buffer holding tile kt
  int rb = 2;          // buffer to refill with tile kt+2 (consumed in group kt-1)
  for (int kt = 0; kt < nk; ++kt) {
    // wait tile kt's own 4 loads (issued one full group ago); tile kt+1's stay in flight
    asm volatile("s_waitcnt vmcnt(4)" ::: "memory");
    __builtin_amdgcn_sched_barrier(0);
    __builtin_amdgcn_s_barrier();   // tile kt visible everywhere; buf rb free

    const int nt = kt + 2;
    const int off = (nt < nk) ? nt * 32 : 0;
    const unsigned aAddr = aBase + (unsigned)cb * 16384u;
    const unsigned bAddr = bBase + (unsigned)cb * 16384u;

    // ---- phase 0: m-half 0 ----
    gload16(aP0 + off, sA + rb * 8192); gload16(aP1 + off, sA + rb * 8192 + 512);
    FragU b0, b1, b2, b3, a0, a1, a2, a3;
    DSREAD(b0.u, bAddr, "0");
    DSREAD(b1.u, bAddr, "1024");
    DSREAD(b2.u, bAddr, "2048");
    DSREAD(b3.u, bAddr, "3072");
    DSREAD(a0.u, aAddr, "0");
    DSREAD(a1.u, aAddr, "1024");
    DSREAD(a2.u, aAddr, "2048");
    DSREAD(a3.u, aAddr, "3072");
    asm volatile("s_waitcnt lgkmcnt(0)" ::: "memory");
    __builtin_amdgcn_sched_barrier(0);      // rule 18
    __builtin_amdgcn_s_setprio(1);
    acc[0][0] = __builtin_amdgcn_mfma_f32_16x16x32_bf16(a0.b, b0.b, acc[0][0], 0, 0, 0);
    acc[0][1] = __builtin_amdgcn_mfma_f32_16x16x32_bf16(a0.b, b1.b, acc[0][1], 0, 0, 0);
    acc[0][2] = __builtin_amdgcn_mfma_f32_16x16x32_bf16(a0.b, b2.b, acc[0][2], 0, 0, 0);
    acc[0][3] = __builtin_amdgcn_mfma_f32_16x16x32_bf16(a0.b, b3.b, acc[0][3], 0, 0, 0);
    acc[1][0] = __builtin_amdgcn_mfma_f32_16x16x32_bf16(a1.b, b0.b, acc[1][0], 0, 0, 0);
    acc[1][1] = __builtin_amdgcn_mfma_f32_16x16x32_bf16(a1.b, b1.b, acc[1][1], 0, 0, 0);
    acc[1][2] = __builtin_amdgcn_mfma_f32_16x16x32_bf16(a1.b, b2.b, acc[1][2], 0, 0, 0);
    acc[1][3] = __builtin_amdgcn_mfma_f32_16x16x32_bf16(a1.b, b3.b, acc[1][3], 0, 0, 0);
    acc[2][0] = __builtin_amdgcn_mfma_f32_16x16x32_bf16(a2.b, b0.b, acc[2][0], 0, 0, 0);
    acc[2][1] = __builtin_amdgcn_mfma_f32_16x16x32_bf16(a2.b, b1.b, acc[2][1], 0, 0, 0);
    acc[2][2] = __builtin_amdgcn_mfma_f32_16x16x32_bf16(a2.b, b2.b, acc[2][2], 0, 0, 0);
    acc[2][3] = __builtin_amdgcn_mfma_f32_16x16x32_bf16(a2.b, b3.b, acc[2][3], 0, 0, 0);
    acc[3][0] = __builtin_amdgcn_mfma_f32_16x16x32_bf16(a3.b, b0.b, acc[3][0], 0, 0, 0);
    acc[3][1] = __builtin_amdgcn_mfma_f32_16x16x32_bf16(a3.b, b1.b, acc[3][1], 0, 0, 0);
    acc[3][2] = __builtin_amdgcn_mfma_f32_16x16x32_bf16(a3.b, b2.b, acc[3][2], 0, 0, 0);
    acc[3][3] = __builtin_amdgcn_mfma_f32_16x16x32_bf16(a3.b, b3.b, acc[3][3], 0, 0, 0);
    __builtin_amdgcn_s_setprio(0);

    // ---- phase 1: m-half 1 (B frags reused) ----
    gload16(wP0 + off, sW + rb * 8192); gload16(wP1 + off, sW + rb * 8192 + 512);
    FragU a4, a5, a6, a7;
    DSREAD(a4.u, aAddr, "4096");
    DSREAD(a5.u, aAddr, "5120");
    DSREAD(a6.u, aAddr, "6144");
    DSREAD(a7.u, aAddr, "7168");
    asm volatile("s_waitcnt lgkmcnt(0)" ::: "memory");
    __builtin_amdgcn_sched_barrier(0);
    __builtin_amdgcn_s_setprio(1);
    acc[4][0] = __builtin_amdgcn_mfma_f32_16x16x32_bf16(a4.b, b0.b, acc[4][0], 0, 0, 0);
    acc[4][1] = __builtin_amdgcn_mfma_f32_16x16x32_bf16(a4.b, b1.b, acc[4][1], 0, 0, 0);
    acc[4][2] = __builtin_amdgcn_mfma_f32_16x16x32_bf16(a4.b, b2.b, acc[4][2], 0, 0, 0);
    acc[4][3] = __builtin_amdgcn_mfma_f32_16x16x32_bf16(a4.b, b3.b, acc[4][3], 0, 0, 0);
    acc[5][0] = __builtin_amdgcn_mfma_f32_16x16x32_bf16(a5.b, b0.b, acc[5][0], 0, 0, 0);
    acc[5][1] = __builtin_amdgcn_mfma_f32_16x16x32_bf16(a5.b, b1.b, acc[5][1], 0, 0, 0);
    acc[5][2] = __builtin_amdgcn_mfma_f32_16x16x32_bf16(a5.b, b2.b, acc[5][2], 0, 0, 0);
    acc[5][3] = __builtin_amdgcn_mfma_f32_16x16x32_bf16(a5.b, b3.b, acc[5][3], 0, 0, 0);
    acc[6][0] = __builtin_amdgcn_mfma_f32_16x16x32_bf16(a6.b, b0.b, acc[6][0], 0, 0, 0);
    acc[6][1] = __builtin_amdgcn_mfma_f32_16x16x32_bf16(a6.b, b1.b, acc[6][1], 0, 0, 0);
    acc[6][2] = __builtin_amdgcn_mfma_f32_16x16x32_bf16(a6.b, b2.b, acc[6][2], 0, 0, 0);
    acc[6][3] = __builtin_amdgcn_mfma_f32_16x16x32_bf16(a6.b, b3.b, acc[6][3], 0, 0, 0);
    acc[7][0] = __builtin_amdgcn_mfma_f32_16x16x32_bf16(a7.b, b0.b, acc[7][0], 0, 0, 0);
    acc[7][1] = __builtin_amdgcn_mfma_f32_16x16x32_bf16(a7.b, b1.b, acc[7][1], 0, 0, 0);
    acc[7][2] = __builtin_amdgcn_mfma_f32_16x16x32_bf16(a7.b, b2.b, acc[7][2], 0, 0, 0);
    acc[7][3] = __builtin_amdgcn_mfma_f32_16x16x32_bf16(a7.b, b3.b, acc[7][3], 0, 0, 0);
    __builtin_amdgcn_s_setprio(0);

    cb = (cb == 2) ? 0 : cb + 1;
    rb = (rb == 2) ? 0 : rb + 1;
  }

  // epilogue: C/D layout col=lane&15, row=(lane>>4)*4+reg
  const int crow = (lane >> 4) * 4, ccol = lane & 15;
  #pragma unroll
  for (int i = 0; i < 8; i++) {
    #pragma unroll
    for (int r = 0; r < 4; r++) {
      int m = bm + wm + i * 16 + crow + r;
      if (m < M) {
        #pragma unroll
        for (int j = 0; j < 4; j++) {
          int n = bn + wn + j * 16 + ccol;
          float v = acc[i][j][r];
          if (bias) v += bias[n];
          if (ACT) v = gelu_f(v);
          if (OUTBF) ((ushortT*)Cb)[(size_t)m * N + n] = (ushortT)f2bf(v);
          else       ((float*)Cb)  [(size_t)m * N + n] = v;
        }
      }
    }
  }
  // drain outstanding dummy DMAs before LDS is deallocated
  asm volatile("s_waitcnt vmcnt(0)" ::: "memory");
}

// ---------- MFMA attention (unchanged) ----------
#define KROWS 208
#define VSTR  232
__global__ __launch_bounds__(256) void attn_mfma(
    const ushortT* __restrict__ qkv, const float* __restrict__ prefix_k,
    const float* __restrict__ prefix_v, const float* __restrict__ act_scale,
    const int* __restrict__ task_id, ushortT* __restrict__ out,
    int layer, int koff)
{
  __shared__ ushortT smem[13312 + 14848 + 4096];   // 64512 B
  ushortT* Kl = smem;
  ushortT* Vt = smem + 13312;
  ushortT* Ps = smem + 13312 + 14848;

  const int tid = threadIdx.x, lane = tid & 63, wid = tid >> 6;
  const int g = lane >> 4, qc = lane & 15;
  const int qh = blockIdx.x, h = blockIdx.y, b = blockIdx.z;
  const int KtA = NTOK + koff;

  int tsk = 0;
  float s0 = 1.f, s1 = 1.f;
  if (koff) {
    tsk = task_id[b]; tsk = tsk < 0 ? 0 : (tsk > TASKS_ - 1 ? TASKS_ - 1 : tsk);
    s0 = act_scale[layer * 2]; s1 = act_scale[layer * 2 + 1];
  }

  {
    uint4* vz = (uint4*)Vt;
    for (int i = tid; i < 14848 / 8; i += 256) vz[i] = (uint4){0, 0, 0, 0};
    uint4* kz = (uint4*)(Kl + 202 * 64);
    if (tid < 48) kz[tid] = (uint4){0, 0, 0, 0};
  }
  __syncthreads();

  for (int u = tid; u < KtA * 8; u += 256) {
    int row = u >> 3, cg = u & 7;
    uint4 val;
    if (row < koff) {
      size_t off = ((((size_t)layer * TASKS_ + tsk) * PL_ + row) * H_ + h) * HD_ + cg * 8;
      float4 f0 = *(const float4*)(prefix_k + off);
      float4 f1 = *(const float4*)(prefix_k + off + 4);
      val.x = f2bf(f0.x) | (f2bf(f0.y) << 16); val.y = f2bf(f0.z) | (f2bf(f0.w) << 16);
      val.z = f2bf(f1.x) | (f2bf(f1.y) << 16); val.w = f2bf(f1.z) | (f2bf(f1.w) << 16);
    } else {
      int n = row - koff;
      val = *(const uint4*)(qkv + ((size_t)b * NTOK + n) * 2304 + D_ + h * HD_ + cg * 8);
    }
    *(uint4*)(Kl + row * 64 + ((cg * 8) ^ ((row & 7) << 3))) = val;
  }
  for (int u = tid; u < KtA * 8; u += 256) {
    int row = u >> 3, dg = u & 7;
    ushortT e[8];
    if (row < koff) {
      size_t off = ((((size_t)layer * TASKS_ + tsk) * PL_ + row) * H_ + h) * HD_ + dg * 8;
      #pragma unroll
      for (int t = 0; t < 8; t++) e[t] = (ushortT)f2bf(prefix_v[off + t]);
    } else {
      int n = row - koff;
      uint4 v = *(const uint4*)(qkv + ((size_t)b * NTOK + n) * 2304 + 2 * D_ + h * HD_ + dg * 8);
      *(uint4*)e = v;
    }
    #pragma unroll
    for (int t = 0; t < 8; t++) Vt[(dg * 8 + t) * VSTR + row] = e[t];
  }
  __syncthreads();

  const int tend = qh ? 13 : 7;
  for (int t = qh * 7 + wid; t < tend; t += 4) {
    const int q0 = t * 16;
    int qr = q0 + qc; if (qr > NTOK - 1) qr = NTOK - 1;
    const ushortT* qp = qkv + ((size_t)b * NTOK + qr) * 2304 + h * HD_ + g * 8;
    bf16x8 qf0 = *(const bf16x8*)qp;
    bf16x8 qf1 = *(const bf16x8*)(qp + 32);

    f32x4 sacc[13];
    #pragma unroll
    for (int kt = 0; kt < 13; kt++) sacc[kt] = (f32x4){0.f, 0.f, 0.f, 0.f};
    #pragma unroll
    for (int kt = 0; kt < 13; kt++) {
      int row = kt * 16 + qc;
      int sw = (row & 7) << 3;
      bf16x8 ka0 = *(const bf16x8*)(Kl + row * 64 + ((g * 8) ^ sw));
      bf16x8 ka1 = *(const bf16x8*)(Kl + row * 64 + ((32 + g * 8) ^ sw));
      sacc[kt] = __builtin_amdgcn_mfma_f32_16x16x32_bf16(ka0, qf0, sacc[kt], 0, 0, 0);
      sacc[kt] = __builtin_amdgcn_mfma_f32_16x16x32_bf16(ka1, qf1, sacc[kt], 0, 0, 0);
    }

    float* sp = (float*)sacc;
    float mx = -1e30f;
    #pragma unroll
    for (int kt = 0; kt < 13; kt++)
      #pragma unroll
      for (int r = 0; r < 4; r++) {
        int k = kt * 16 + g * 4 + r;
        float s = sp[kt * 4 + r] * SCALE_;
        if (koff && k < PL_) s += s1 / (1.f + __expf(-s * s0));
        if (k >= KtA) s = -1e30f;
        sp[kt * 4 + r] = s;
        mx = fmaxf(mx, s);
      }
    mx = fmaxf(mx, __shfl_xor(mx, 16));
    mx = fmaxf(mx, __shfl_xor(mx, 32));
    float sum = 0.f;
    #pragma unroll
    for (int i = 0; i < 52; i++) { float p = __expf(sp[i] - mx); sp[i] = p; sum += p; }
    sum += __shfl_xor(sum, 16);
    sum += __shfl_xor(sum, 32);
    const float inv = 1.f / sum;

    f32x4 oacc[4];
    #pragma unroll
    for (int d = 0; d < 4; d++) oacc[d] = (f32x4){0.f, 0.f, 0.f, 0.f};
    #pragma unroll
    for (int c = 0; c < 7; c++) {
      ushortT* slab = Ps + wid * 1024 + (c & 1) * 512;
      uint2 w0, w1;
      {
        float p0 = sp[8 * c + 0] * inv, p1 = sp[8 * c + 1] * inv;
        float p2 = sp[8 * c + 2] * inv, p3 = sp[8 * c + 3] * inv;
        w0.x = f2bf(p0) | (f2bf(p1) << 16); w0.y = f2bf(p2) | (f2bf(p3) << 16);
      }
      if (c < 6) {
        float p0 = sp[8 * c + 4] * inv, p1 = sp[8 * c + 5] * inv;
        float p2 = sp[8 * c + 6] * inv, p3 = sp[8 * c + 7] * inv;
        w1.x = f2bf(p0) | (f2bf(p1) << 16); w1.y = f2bf(p2) | (f2bf(p3) << 16);
      } else { w1.x = 0; w1.y = 0; }
      *(uint2*)(slab + qc * 32 + g * 4) = w0;
      *(uint2*)(slab + qc * 32 + 16 + g * 4) = w1;
      bf16x8 pa = *(const bf16x8*)(slab + qc * 32 + g * 8);
      #pragma unroll
      for (int dt = 0; dt < 4; dt++) {
        bf16x8 vb = *(const bf16x8*)(Vt + (dt * 16 + qc) * VSTR + c * 32 + g * 8);
        oacc[dt] = __builtin_amdgcn_mfma_f32_16x16x32_bf16(pa, vb, oacc[dt], 0, 0, 0);
      }
    }

    #pragma unroll
    for (int r = 0; r < 4; r++) {
      int q = q0 + g * 4 + r;
      if (q < NTOK) {
        size_t ro = ((size_t)b * NTOK + q) * D_ + h * HD_;
        #pragma unroll
        for (int dt = 0; dt < 4; dt++)
          out[ro + dt * 16 + qc] = (ushortT)f2bf(oacc[dt][r]);
      }
    }
  }
}

// ---------- launch ----------
extern "C" void kernel_launch(void* const* d_in, const int* in_sizes, int n_in,
                              void* d_out, int out_size, void* d_ws, size_t ws_size,
                              hipStream_t stream)
{
  (void)in_sizes; (void)n_in; (void)out_size; (void)ws_size;
  const float* x         = (const float*)d_in[0];
  const int*   task_id   = (const int*)  d_in[1];
  const float* patch_w   = (const float*)d_in[2];
  const float* patch_b   = (const float*)d_in[3];
  const float* cls_token = (const float*)d_in[4];
  const float* pos_embed = (const float*)d_in[5];
  const float* ln1_w     = (const float*)d_in[6];
  const float* ln1_b     = (const float*)d_in[7];
  const float* qkv_w     = (const float*)d_in[8];
  const float* qkv_b     = (const float*)d_in[9];
  const float* proj_w    = (const float*)d_in[10];
  const float* proj_b    = (const float*)d_in[11];
  const float* ln2_w     = (const float*)d_in[12];
  const float* ln2_b     = (const float*)d_in[13];
  const float* fc1_w     = (const float*)d_in[14];
  const float* fc1_b     = (const float*)d_in[15];
  const float* fc2_w     = (const float*)d_in[16];
  const float* fc2_b     = (const float*)d_in[17];
  const float* norm_w    = (const float*)d_in[18];
  const float* norm_b    = (const float*)d_in[19];
  const float* prefix_k  = (const float*)d_in[20];
  const float* prefix_v  = (const float*)d_in[21];
  const float* act_scale = (const float*)d_in[22];
  float* out = (float*)d_out;

  char* wsb = (char*)d_ws;
  float*   h      = (float*)  (wsb);
  ushortT* actA   = (ushortT*)(wsb + 19365888);
  ushortT* qkvbuf = (ushortT*)(wsb + 29048832);   // also fc2 partials (3*PSZ elems)
  ushortT* mlpbuf = (ushortT*)(wsb + 58097664);
  ushortT* wsc    = (ushortT*)(wsb + 96829440);
  float*   peout  = (float*)qkvbuf;

  ushortT* wqkv  = wsc;
  ushortT* wproj = wsc + 1769472;
  ushortT* wfc1  = wsc + 2359296;
  ushortT* wfc2  = wsc + 4718592;

  // ---- patch embedding ----
  convw1_kernel<<<288, 256, 0, stream>>>(patch_w, wsc, 73728);
  im2col_kernel<<<(B_ * NPATCH * D_ + 255) / 256, 256, 0, stream>>>(x, actA);
  gemm_mfma<0,0,0><<<dim3(12, 49), 256, 0, stream>>>(
      actA, wsc, nullptr, nullptr, peout, B_ * NPATCH, D_, D_, D_, D_);
  assemble_kernel<<<(ROWS * D_ + 255) / 256, 256, 0, stream>>>(
      peout, patch_b, cls_token, pos_embed, h);

  // ---- transformer layers ----
  for (int i = 0; i < DEPTH_; i++) {
    convw4_kernel<<<3456, 256, 0, stream>>>(
        qkv_w + (size_t)i * 1769472, proj_w + (size_t)i * 589824,
        fc1_w + (size_t)i * 2359296, fc2_w + (size_t)i * 2359296, wsc);
    ln_kernel<1><<<ROWS, 256, 0, stream>>>(h, D_, ln1_w + i * D_, ln1_b + i * D_, actA, D_);
    gemm_wide<1,0><<<dim3(9, 25), 512, 0, stream>>>(
        actA, wqkv, qkv_b + i * 3 * D_, qkvbuf, ROWS, 3 * D_, D_, D_, D_);
    attn_mfma<<<dim3(2, H_, B_), 256, 0, stream>>>(
        qkvbuf, prefix_k, prefix_v, act_scale, task_id, actA, i, (i < NPL_) ? PL_ : 0);
    gemm_mfma<0,0,1><<<dim3(12, 50), 256, 0, stream>>>(
        actA, wproj, proj_b + i * D_, h, h, ROWS, D_, D_, D_, D_);
    ln_kernel<1><<<ROWS, 256, 0, stream>>>(h, D_, ln2_w + i * D_, ln2_b + i * D_, actA, D_);
    gemm_wide<1,1><<<dim3(12, 25), 512, 0, stream>>>(
        actA, wfc1, fc1_b + i * MLPD_, mlpbuf, ROWS, MLPD_, D_, D_, D_);
    // fc2 split-K x3: bf16 partials -> qkvbuf
    gemm_wide<1,0><<<dim3(3, 25, 3), 512, 0, stream>>>(
        mlpbuf, wfc2, nullptr, qkvbuf, ROWS, D_, MLPD_ / 3, MLPD_, MLPD_);
    reduce3_kernel<<<PSZ / 8 / 256, 256, 0, stream>>>(qkvbuf, fc2_b + i * D_, h);
  }

  ln_kernel<0><<<B_, 256, 0, stream>>>(h, (size_t)NTOK * D_, norm_w, norm_b, out, D_);
}

// Round 12
// 3179.411 us; speedup vs baseline: 1.2623x; 1.2623x over previous
//
#include <hip/hip_runtime.h>
#include <hip/hip_bf16.h>

#define B_     32
#define NTOK   197
#define NPATCH 196
#define D_     768
#define H_     12
#define HD_    64
#define DEPTH_ 12
#define MLPD_  3072
#define TASKS_ 10
#define PL_    5
#define NPL_   5
#define SCALE_ 0.125f
#define ROWS   (B_*NTOK)   // 6304
#define PSZ    (ROWS*D_)   // 4,841,472 per split-K partial

typedef unsigned short ushortT;
typedef __bf16 bf16x8 __attribute__((ext_vector_type(8)));
typedef float  f32x4  __attribute__((ext_vector_type(4)));
typedef unsigned int u32x4 __attribute__((ext_vector_type(4)));

union FragU { u32x4 u; bf16x8 b; };

// ---------- helpers ----------
__device__ inline unsigned int f2bf(float f){
  unsigned int u = __float_as_uint(f);
  return (u + 0x7fffu + ((u >> 16) & 1u)) >> 16;   // RNE to bf16
}
__device__ inline float bf2f(ushortT u){ return __uint_as_float(((unsigned)u) << 16); }
__device__ inline float gelu_f(float x){ return 0.5f * x * (1.f + erff(x * 0.70710678118f)); }

__device__ inline void gload16(const void* g, void* l){
  __builtin_amdgcn_global_load_lds(
      (const __attribute__((address_space(1))) void*)(uintptr_t)g,
      (__attribute__((address_space(3))) void*)(uintptr_t)l,
      16, 0, 0);
}

#define DSREAD(dst, addr, OFFS) \
  asm volatile("ds_read_b128 %0, %1 offset:" OFFS : "=v"(dst) : "v"(addr))

// ---------- weight conversion fp32 -> bf16 ----------
__global__ __launch_bounds__(256) void convw4_kernel(const float* __restrict__ s0,
    const float* __restrict__ s1, const float* __restrict__ s2, const float* __restrict__ s3,
    ushortT* __restrict__ dst)
{
  int idx = blockIdx.x * 256 + threadIdx.x;
  int e = idx * 8;
  if (e >= 7077888) return;
  const float* s; int loc;
  if (e < 1769472)      { s = s0; loc = e; }
  else if (e < 2359296) { s = s1; loc = e - 1769472; }
  else if (e < 4718592) { s = s2; loc = e - 2359296; }
  else                  { s = s3; loc = e - 4718592; }
  float4 a = *(const float4*)(s + loc);
  float4 c = *(const float4*)(s + loc + 4);
  uint4 o;
  o.x = f2bf(a.x) | (f2bf(a.y) << 16);
  o.y = f2bf(a.z) | (f2bf(a.w) << 16);
  o.z = f2bf(c.x) | (f2bf(c.y) << 16);
  o.w = f2bf(c.z) | (f2bf(c.w) << 16);
  *(uint4*)(dst + e) = o;
}

__global__ __launch_bounds__(256) void convw1_kernel(const float* __restrict__ s,
    ushortT* __restrict__ dst, int n8)
{
  int idx = blockIdx.x * 256 + threadIdx.x;
  if (idx >= n8) return;
  int e = idx * 8;
  float4 a = *(const float4*)(s + e);
  float4 c = *(const float4*)(s + e + 4);
  uint4 o;
  o.x = f2bf(a.x) | (f2bf(a.y) << 16);
  o.y = f2bf(a.z) | (f2bf(a.w) << 16);
  o.z = f2bf(c.x) | (f2bf(c.y) << 16);
  o.w = f2bf(c.z) | (f2bf(c.w) << 16);
  *(uint4*)(dst + e) = o;
}

// ---------- im2col (bf16 out) ----------
__global__ __launch_bounds__(256) void im2col_kernel(const float* __restrict__ x,
                                                     ushortT* __restrict__ out)
{
  int idx = blockIdx.x * 256 + threadIdx.x;
  const int tot = B_ * NPATCH * D_;
  if (idx >= tot) return;
  int m = idx / D_, k = idx - m * D_;
  int b = m / NPATCH, p = m - b * NPATCH;
  int pr = p / 14, pc = p - pr * 14;
  int c = k >> 8, r = k & 255;
  int py = r >> 4, px = r & 15;
  float v = x[(((size_t)(b * 3 + c) * 224) + pr * 16 + py) * 224 + pc * 16 + px];
  out[idx] = (ushortT)f2bf(v);
}

// ---------- assemble h0 = [cls; patches+patch_b] + pos (fp32) ----------
__global__ __launch_bounds__(256) void assemble_kernel(const float* __restrict__ pe,
    const float* __restrict__ patch_b, const float* __restrict__ cls,
    const float* __restrict__ pos, float* __restrict__ h)
{
  int idx = blockIdx.x * 256 + threadIdx.x;
  const int tot = ROWS * D_;
  if (idx >= tot) return;
  int bn = idx / D_, d = idx - bn * D_;
  int b = bn / NTOK, n = bn - b * NTOK;
  float v;
  if (n == 0) v = cls[d];
  else        v = pe[((size_t)b * NPATCH + (n - 1)) * D_ + d] + patch_b[d];
  h[idx] = v + pos[(size_t)n * D_ + d];
}

// ---------- fused split-K reduce (+bias) into h, optionally followed by LayerNorm ----------
// One block per row. h[row] += sum_q p_q[row] + bias; if DOLN, y[row] = LN(h[row]) in bf16.
template<int NP, int DOLN>
__global__ __launch_bounds__(256) void reduce_ln_kernel(
    const ushortT* __restrict__ p, const float* __restrict__ bias,
    float* __restrict__ h, const float* __restrict__ lw,
    const float* __restrict__ lb, ushortT* __restrict__ y)
{
  const size_t base = (size_t)blockIdx.x * D_;
  const int t = threadIdx.x;
  float vals[3];
  float s = 0.f, ss = 0.f;
  #pragma unroll
  for (int e = 0; e < 3; e++) {
    int d = t + e * 256;
    size_t idx = base + d;
    float acc = h[idx] + bias[d];
    #pragma unroll
    for (int q = 0; q < NP; q++) acc += bf2f(p[(size_t)q * PSZ + idx]);
    h[idx] = acc;
    vals[e] = acc; s += acc; ss += acc * acc;
  }
  if (DOLN) {
    #pragma unroll
    for (int off = 32; off >= 1; off >>= 1) {
      s  += __shfl_down(s, off);
      ss += __shfl_down(ss, off);
    }
    __shared__ float sm[4], ssm[4];
    int wid = t >> 6, lane = t & 63;
    if (lane == 0) { sm[wid] = s; ssm[wid] = ss; }
    __syncthreads();
    s  = sm[0] + sm[1] + sm[2] + sm[3];
    ss = ssm[0] + ssm[1] + ssm[2] + ssm[3];
    float mean = s * (1.f / D_);
    float var  = ss * (1.f / D_) - mean * mean;
    float inv  = rsqrtf(var + 1e-6f);
    #pragma unroll
    for (int e = 0; e < 3; e++) {
      int d = t + e * 256;
      y[base + d] = (ushortT)f2bf((vals[e] - mean) * inv * lw[d] + lb[d]);
    }
  }
}

// ---------- LayerNorm (one block per row), templated output ----------
template<int OUTBF>
__global__ __launch_bounds__(256) void ln_kernel(const float* __restrict__ x, size_t xstride,
    const float* __restrict__ w, const float* __restrict__ b,
    void* __restrict__ y, size_t ystride)
{
  const float* xr = x + (size_t)blockIdx.x * xstride;
  float vals[3];
  float s = 0.f, ss = 0.f;
  #pragma unroll
  for (int t = 0; t < 3; t++) {
    float v = xr[threadIdx.x + t * 256];
    vals[t] = v; s += v; ss += v * v;
  }
  #pragma unroll
  for (int off = 32; off >= 1; off >>= 1) {
    s  += __shfl_down(s, off);
    ss += __shfl_down(ss, off);
  }
  __shared__ float sm[4], ssm[4];
  int wid = threadIdx.x >> 6, lane = threadIdx.x & 63;
  if (lane == 0) { sm[wid] = s; ssm[wid] = ss; }
  __syncthreads();
  s  = sm[0] + sm[1] + sm[2] + sm[3];
  ss = ssm[0] + ssm[1] + ssm[2] + ssm[3];
  float mean = s * (1.f / D_);
  float var  = ss * (1.f / D_) - mean * mean;
  float inv  = rsqrtf(var + 1e-6f);
  #pragma unroll
  for (int t = 0; t < 3; t++) {
    int d = threadIdx.x + t * 256;
    float v = (vals[t] - mean) * inv * w[d] + b[d];
    if (OUTBF) ((ushortT*)y)[(size_t)blockIdx.x * ystride + d] = (ushortT)f2bf(v);
    else       ((float*)y)  [(size_t)blockIdx.x * ystride + d] = v;
  }
}

// ---------- high-occupancy bf16 MFMA GEMM: 128x64 tile, wave=64x32, 6 blocks/CU ----------
// acc 4x2 (32 AGPR); LDS 24KB (A [2][4096] @0, W [2][2048] @ elem 8192);
// 3 staging loads/wave/tile, counted vmcnt(3) depth-2 pipeline.
// Swizzle: source col chunk (L&3)^((L>>3)&3) pre-swizzle; read slot kc^((rsel>>1)&3).
template<int OUTBF, int ACT, int HASRES>
__global__ __launch_bounds__(256, 6) void gemm_mfma(
    const ushortT* __restrict__ A, const ushortT* __restrict__ W,
    const float* __restrict__ bias, const float* __restrict__ resid,
    void* __restrict__ Cout, int M, int N, int K, int LDA, int LDW)
{
  __shared__ ushortT lds[12288];   // 24 KB
  const int tid = threadIdx.x, lane = tid & 63, wid = tid >> 6;
  const int bm = blockIdx.y * 128, bn = blockIdx.x * 64;
  const int wm = (wid >> 1) * 64, wn = (wid & 1) * 32;
  const int kz = blockIdx.z;
  A += (size_t)kz * K; W += (size_t)kz * K;
  char* Cb = (char*)Cout + (size_t)kz * M * N * (OUTBF ? 2 : 4);

  const int srow = lane >> 2;
  const int scol = ((lane & 3) ^ ((lane >> 3) & 3)) * 8;
  int arow0 = bm + (2 * wid) * 16 + srow;     if (arow0 > M - 1) arow0 = M - 1;
  int arow1 = bm + (2 * wid + 1) * 16 + srow; if (arow1 > M - 1) arow1 = M - 1;
  const int wrow = bn + wid * 16 + srow;
  const ushortT* aP0 = A + (size_t)arow0 * LDA + scol;
  const ushortT* aP1 = A + (size_t)arow1 * LDA + scol;
  const ushortT* wP0 = W + (size_t)wrow * LDW + scol;
  ushortT* sA = lds + 2 * wid * 512;
  ushortT* sW = lds + 8192 + wid * 512;

  f32x4 acc[4][2];
  #pragma unroll
  for (int i = 0; i < 4; i++)
    #pragma unroll
    for (int j = 0; j < 2; j++)
      acc[i][j] = (f32x4){0.f, 0.f, 0.f, 0.f};

  const int rsel = lane & 15, kc = lane >> 4;
  const unsigned ldsbase = (unsigned)(size_t)&lds[0];
  const unsigned rowoff = (unsigned)(rsel * 64 + ((kc ^ ((rsel >> 1) & 3)) << 4));
  const unsigned aBase = ldsbase + (unsigned)(wm * 64) + rowoff;
  const unsigned bBase = ldsbase + 16384u + (unsigned)(wn * 64) + rowoff;

  const int nk = K >> 5;

  #pragma unroll
  for (int p = 0; p < 2; ++p) {
    const int off = p * 32;
    gload16(aP0 + off, sA + p * 4096); gload16(aP1 + off, sA + p * 4096 + 512);
    gload16(wP0 + off, sW + p * 2048);
  }

  for (int kt = 0; kt < nk; ++kt) {
    const int cb = kt & 1;
    asm volatile("s_waitcnt vmcnt(3)" ::: "memory");
    __builtin_amdgcn_sched_barrier(0);
    __builtin_amdgcn_s_barrier();

    const unsigned aAddr = aBase + (unsigned)cb * 8192u;
    const unsigned bAddr = bBase + (unsigned)cb * 4096u;
    FragU fa0, fa1, fa2, fa3, fb0, fb1;
    DSREAD(fa0.u, aAddr, "0");
    DSREAD(fa1.u, aAddr, "1024");
    DSREAD(fa2.u, aAddr, "2048");
    DSREAD(fa3.u, aAddr, "3072");
    DSREAD(fb0.u, bAddr, "0");
    DSREAD(fb1.u, bAddr, "1024");
    asm volatile("s_waitcnt lgkmcnt(0)" ::: "memory");
    __builtin_amdgcn_sched_barrier(0);
    __builtin_amdgcn_s_barrier();

    const int nt = kt + 2;
    const int off = (nt < nk) ? nt * 32 : 0;
    gload16(aP0 + off, sA + cb * 4096); gload16(aP1 + off, sA + cb * 4096 + 512);
    gload16(wP0 + off, sW + cb * 2048);

    acc[0][0] = __builtin_amdgcn_mfma_f32_16x16x32_bf16(fa0.b, fb0.b, acc[0][0], 0, 0, 0);
    acc[0][1] = __builtin_amdgcn_mfma_f32_16x16x32_bf16(fa0.b, fb1.b, acc[0][1], 0, 0, 0);
    acc[1][0] = __builtin_amdgcn_mfma_f32_16x16x32_bf16(fa1.b, fb0.b, acc[1][0], 0, 0, 0);
    acc[1][1] = __builtin_amdgcn_mfma_f32_16x16x32_bf16(fa1.b, fb1.b, acc[1][1], 0, 0, 0);
    acc[2][0] = __builtin_amdgcn_mfma_f32_16x16x32_bf16(fa2.b, fb0.b, acc[2][0], 0, 0, 0);
    acc[2][1] = __builtin_amdgcn_mfma_f32_16x16x32_bf16(fa2.b, fb1.b, acc[2][1], 0, 0, 0);
    acc[3][0] = __builtin_amdgcn_mfma_f32_16x16x32_bf16(fa3.b, fb0.b, acc[3][0], 0, 0, 0);
    acc[3][1] = __builtin_amdgcn_mfma_f32_16x16x32_bf16(fa3.b, fb1.b, acc[3][1], 0, 0, 0);
  }

  const int crow = (lane >> 4) * 4, ccol = lane & 15;
  #pragma unroll
  for (int i = 0; i < 4; i++) {
    #pragma unroll
    for (int r = 0; r < 4; r++) {
      int m = bm + wm + i * 16 + crow + r;
      if (m < M) {
        #pragma unroll
        for (int j = 0; j < 2; j++) {
          int n = bn + wn + j * 16 + ccol;
          float v = acc[i][j][r];
          if (bias) v += bias[n];
          if (ACT) v = gelu_f(v);
          if (HASRES) v += resid[(size_t)m * N + n];
          if (OUTBF) ((ushortT*)Cb)[(size_t)m * N + n] = (ushortT)f2bf(v);
          else       ((float*)Cb)  [(size_t)m * N + n] = v;
        }
      }
    }
  }
  asm volatile("s_waitcnt vmcnt(0)" ::: "memory");
}

// ---------- MFMA attention (unchanged) ----------
#define KROWS 208
#define VSTR  232
__global__ __launch_bounds__(256) void attn_mfma(
    const ushortT* __restrict__ qkv, const float* __restrict__ prefix_k,
    const float* __restrict__ prefix_v, const float* __restrict__ act_scale,
    const int* __restrict__ task_id, ushortT* __restrict__ out,
    int layer, int koff)
{
  __shared__ ushortT smem[13312 + 14848 + 4096];   // 64512 B
  ushortT* Kl = smem;
  ushortT* Vt = smem + 13312;
  ushortT* Ps = smem + 13312 + 14848;

  const int tid = threadIdx.x, lane = tid & 63, wid = tid >> 6;
  const int g = lane >> 4, qc = lane & 15;
  const int qh = blockIdx.x, h = blockIdx.y, b = blockIdx.z;
  const int KtA = NTOK + koff;

  int tsk = 0;
  float s0 = 1.f, s1 = 1.f;
  if (koff) {
    tsk = task_id[b]; tsk = tsk < 0 ? 0 : (tsk > TASKS_ - 1 ? TASKS_ - 1 : tsk);
    s0 = act_scale[layer * 2]; s1 = act_scale[layer * 2 + 1];
  }

  {
    uint4* vz = (uint4*)Vt;
    for (int i = tid; i < 14848 / 8; i += 256) vz[i] = (uint4){0, 0, 0, 0};
    uint4* kz = (uint4*)(Kl + 202 * 64);
    if (tid < 48) kz[tid] = (uint4){0, 0, 0, 0};
  }
  __syncthreads();

  for (int u = tid; u < KtA * 8; u += 256) {
    int row = u >> 3, cg = u & 7;
    uint4 val;
    if (row < koff) {
      size_t off = ((((size_t)layer * TASKS_ + tsk) * PL_ + row) * H_ + h) * HD_ + cg * 8;
      float4 f0 = *(const float4*)(prefix_k + off);
      float4 f1 = *(const float4*)(prefix_k + off + 4);
      val.x = f2bf(f0.x) | (f2bf(f0.y) << 16); val.y = f2bf(f0.z) | (f2bf(f0.w) << 16);
      val.z = f2bf(f1.x) | (f2bf(f1.y) << 16); val.w = f2bf(f1.z) | (f2bf(f1.w) << 16);
    } else {
      int n = row - koff;
      val = *(const uint4*)(qkv + ((size_t)b * NTOK + n) * 2304 + D_ + h * HD_ + cg * 8);
    }
    *(uint4*)(Kl + row * 64 + ((cg * 8) ^ ((row & 7) << 3))) = val;
  }
  for (int u = tid; u < KtA * 8; u += 256) {
    int row = u >> 3, dg = u & 7;
    ushortT e[8];
    if (row < koff) {
      size_t off = ((((size_t)layer * TASKS_ + tsk) * PL_ + row) * H_ + h) * HD_ + dg * 8;
      #pragma unroll
      for (int t = 0; t < 8; t++) e[t] = (ushortT)f2bf(prefix_v[off + t]);
    } else {
      int n = row - koff;
      uint4 v = *(const uint4*)(qkv + ((size_t)b * NTOK + n) * 2304 + 2 * D_ + h * HD_ + dg * 8);
      *(uint4*)e = v;
    }
    #pragma unroll
    for (int t = 0; t < 8; t++) Vt[(dg * 8 + t) * VSTR + row] = e[t];
  }
  __syncthreads();

  const int tend = qh ? 13 : 7;
  for (int t = qh * 7 + wid; t < tend; t += 4) {
    const int q0 = t * 16;
    int qr = q0 + qc; if (qr > NTOK - 1) qr = NTOK - 1;
    const ushortT* qp = qkv + ((size_t)b * NTOK + qr) * 2304 + h * HD_ + g * 8;
    bf16x8 qf0 = *(const bf16x8*)qp;
    bf16x8 qf1 = *(const bf16x8*)(qp + 32);

    f32x4 sacc[13];
    #pragma unroll
    for (int kt = 0; kt < 13; kt++) sacc[kt] = (f32x4){0.f, 0.f, 0.f, 0.f};
    #pragma unroll
    for (int kt = 0; kt < 13; kt++) {
      int row = kt * 16 + qc;
      int sw = (row & 7) << 3;
      bf16x8 ka0 = *(const bf16x8*)(Kl + row * 64 + ((g * 8) ^ sw));
      bf16x8 ka1 = *(const bf16x8*)(Kl + row * 64 + ((32 + g * 8) ^ sw));
      sacc[kt] = __builtin_amdgcn_mfma_f32_16x16x32_bf16(ka0, qf0, sacc[kt], 0, 0, 0);
      sacc[kt] = __builtin_amdgcn_mfma_f32_16x16x32_bf16(ka1, qf1, sacc[kt], 0, 0, 0);
    }

    float* sp = (float*)sacc;
    float mx = -1e30f;
    #pragma unroll
    for (int kt = 0; kt < 13; kt++)
      #pragma unroll
      for (int r = 0; r < 4; r++) {
        int k = kt * 16 + g * 4 + r;
        float s = sp[kt * 4 + r] * SCALE_;
        if (koff && k < PL_) s += s1 / (1.f + __expf(-s * s0));
        if (k >= KtA) s = -1e30f;
        sp[kt * 4 + r] = s;
        mx = fmaxf(mx, s);
      }
    mx = fmaxf(mx, __shfl_xor(mx, 16));
    mx = fmaxf(mx, __shfl_xor(mx, 32));
    float sum = 0.f;
    #pragma unroll
    for (int i = 0; i < 52; i++) { float p = __expf(sp[i] - mx); sp[i] = p; sum += p; }
    sum += __shfl_xor(sum, 16);
    sum += __shfl_xor(sum, 32);
    const float inv = 1.f / sum;

    f32x4 oacc[4];
    #pragma unroll
    for (int d = 0; d < 4; d++) oacc[d] = (f32x4){0.f, 0.f, 0.f, 0.f};
    #pragma unroll
    for (int c = 0; c < 7; c++) {
      ushortT* slab = Ps + wid * 1024 + (c & 1) * 512;
      uint2 w0, w1;
      {
        float p0 = sp[8 * c + 0] * inv, p1 = sp[8 * c + 1] * inv;
        float p2 = sp[8 * c + 2] * inv, p3 = sp[8 * c + 3] * inv;
        w0.x = f2bf(p0) | (f2bf(p1) << 16); w0.y = f2bf(p2) | (f2bf(p3) << 16);
      }
      if (c < 6) {
        float p0 = sp[8 * c + 4] * inv, p1 = sp[8 * c + 5] * inv;
        float p2 = sp[8 * c + 6] * inv, p3 = sp[8 * c + 7] * inv;
        w1.x = f2bf(p0) | (f2bf(p1) << 16); w1.y = f2bf(p2) | (f2bf(p3) << 16);
      } else { w1.x = 0; w1.y = 0; }
      *(uint2*)(slab + qc * 32 + g * 4) = w0;
      *(uint2*)(slab + qc * 32 + 16 + g * 4) = w1;
      bf16x8 pa = *(const bf16x8*)(slab + qc * 32 + g * 8);
      #pragma unroll
      for (int dt = 0; dt < 4; dt++) {
        bf16x8 vb = *(const bf16x8*)(Vt + (dt * 16 + qc) * VSTR + c * 32 + g * 8);
        oacc[dt] = __builtin_amdgcn_mfma_f32_16x16x32_bf16(pa, vb, oacc[dt], 0, 0, 0);
      }
    }

    #pragma unroll
    for (int r = 0; r < 4; r++) {
      int q = q0 + g * 4 + r;
      if (q < NTOK) {
        size_t ro = ((size_t)b * NTOK + q) * D_ + h * HD_;
        #pragma unroll
        for (int dt = 0; dt < 4; dt++)
          out[ro + dt * 16 + qc] = (ushortT)f2bf(oacc[dt][r]);
      }
    }
  }
}

// ---------- launch ----------
extern "C" void kernel_launch(void* const* d_in, const int* in_sizes, int n_in,
                              void* d_out, int out_size, void* d_ws, size_t ws_size,
                              hipStream_t stream)
{
  (void)in_sizes; (void)n_in; (void)out_size; (void)ws_size;
  const float* x         = (const float*)d_in[0];
  const int*   task_id   = (const int*)  d_in[1];
  const float* patch_w   = (const float*)d_in[2];
  const float* patch_b   = (const float*)d_in[3];
  const float* cls_token = (const float*)d_in[4];
  const float* pos_embed = (const float*)d_in[5];
  const float* ln1_w     = (const float*)d_in[6];
  const float* ln1_b     = (const float*)d_in[7];
  const float* qkv_w     = (const float*)d_in[8];
  const float* qkv_b     = (const float*)d_in[9];
  const float* proj_w    = (const float*)d_in[10];
  const float* proj_b    = (const float*)d_in[11];
  const float* ln2_w     = (const float*)d_in[12];
  const float* ln2_b     = (const float*)d_in[13];
  const float* fc1_w     = (const float*)d_in[14];
  const float* fc1_b     = (const float*)d_in[15];
  const float* fc2_w     = (const float*)d_in[16];
  const float* fc2_b     = (const float*)d_in[17];
  const float* norm_w    = (const float*)d_in[18];
  const float* norm_b    = (const float*)d_in[19];
  const float* prefix_k  = (const float*)d_in[20];
  const float* prefix_v  = (const float*)d_in[21];
  const float* act_scale = (const float*)d_in[22];
  float* out = (float*)d_out;

  char* wsb = (char*)d_ws;
  float*   h      = (float*)  (wsb);
  ushortT* actA   = (ushortT*)(wsb + 19365888);
  ushortT* qkvbuf = (ushortT*)(wsb + 29048832);   // also split-K partials (up to 3*PSZ elems)
  ushortT* mlpbuf = (ushortT*)(wsb + 58097664);
  ushortT* wsc    = (ushortT*)(wsb + 96829440);
  float*   peout  = (float*)qkvbuf;

  ushortT* wqkv  = wsc;
  ushortT* wproj = wsc + 1769472;
  ushortT* wfc1  = wsc + 2359296;
  ushortT* wfc2  = wsc + 4718592;

  // ---- patch embedding ----
  convw1_kernel<<<288, 256, 0, stream>>>(patch_w, wsc, 73728);
  im2col_kernel<<<(B_ * NPATCH * D_ + 255) / 256, 256, 0, stream>>>(x, actA);
  gemm_mfma<0,0,0><<<dim3(12, 49), 256, 0, stream>>>(
      actA, wsc, nullptr, nullptr, peout, B_ * NPATCH, D_, D_, D_, D_);
  assemble_kernel<<<(ROWS * D_ + 255) / 256, 256, 0, stream>>>(
      peout, patch_b, cls_token, pos_embed, h);

  // ln1 of layer 0 (subsequent ln1's fused into reduce_ln after fc2)
  ln_kernel<1><<<ROWS, 256, 0, stream>>>(h, D_, ln1_w, ln1_b, actA, D_);

  // ---- transformer layers ----
  for (int i = 0; i < DEPTH_; i++) {
    convw4_kernel<<<3456, 256, 0, stream>>>(
        qkv_w + (size_t)i * 1769472, proj_w + (size_t)i * 589824,
        fc1_w + (size_t)i * 2359296, fc2_w + (size_t)i * 2359296, wsc);
    // qkv (actA holds ln1_i output)
    gemm_mfma<1,0,0><<<dim3(36, 50), 256, 0, stream>>>(
        actA, wqkv, qkv_b + i * 3 * D_, nullptr, qkvbuf, ROWS, 3 * D_, D_, D_, D_);
    attn_mfma<<<dim3(2, H_, B_), 256, 0, stream>>>(
        qkvbuf, prefix_k, prefix_v, act_scale, task_id, actA, i, (i < NPL_) ? PL_ : 0);
    // proj split-K x2: bf16 partials -> qkvbuf (attn already consumed it)
    gemm_mfma<1,0,0><<<dim3(12, 50, 2), 256, 0, stream>>>(
        actA, wproj, nullptr, nullptr, qkvbuf, ROWS, D_, D_ / 2, D_, D_);
    // h += p0+p1+proj_b ; ln2 -> actA
    reduce_ln_kernel<2,1><<<ROWS, 256, 0, stream>>>(
        qkvbuf, proj_b + i * D_, h, ln2_w + i * D_, ln2_b + i * D_, actA);
    // fc1
    gemm_mfma<1,1,0><<<dim3(48, 50), 256, 0, stream>>>(
        actA, wfc1, fc1_b + i * MLPD_, nullptr, mlpbuf, ROWS, MLPD_, D_, D_, D_);
    // fc2 split-K x3: bf16 partials -> qkvbuf
    gemm_mfma<1,0,0><<<dim3(12, 50, 3), 256, 0, stream>>>(
        mlpbuf, wfc2, nullptr, nullptr, qkvbuf, ROWS, D_, MLPD_ / 3, MLPD_, MLPD_);
    // h += p0+p1+p2+fc2_b ; ln1 of next layer -> actA (last layer: no LN)
    if (i < DEPTH_ - 1) {
      reduce_ln_kernel<3,1><<<ROWS, 256, 0, stream>>>(
          qkvbuf, fc2_b + i * D_, h, ln1_w + (i + 1) * D_, ln1_b + (i + 1) * D_, actA);
    } else {
      reduce_ln_kernel<3,0><<<ROWS, 256, 0, stream>>>(
          qkvbuf, fc2_b + i * D_, h, nullptr, nullptr, nullptr);
    }
  }

  // ---- final LN on token 0 only ----
  ln_kernel<0><<<B_, 256, 0, stream>>>(h, (size_t)NTOK * D_, norm_w, norm_b, out, D_);
}

// Round 14
// 3175.479 us; speedup vs baseline: 1.2638x; 1.0012x over previous
//
#include <hip/hip_runtime.h>
#include <hip/hip_bf16.h>

#define B_     32
#define NTOK   197
#define NPATCH 196
#define D_     768
#define H_     12
#define HD_    64
#define DEPTH_ 12
#define MLPD_  3072
#define TASKS_ 10
#define PL_    5
#define NPL_   5
#define SCALE_ 0.125f
#define ROWS   (B_*NTOK)   // 6304
#define PSZ    (ROWS*D_)   // per split-K partial

typedef unsigned short ushortT;
typedef __bf16 bf16x8 __attribute__((ext_vector_type(8)));
typedef float  f32x4  __attribute__((ext_vector_type(4)));
typedef unsigned int u32x4 __attribute__((ext_vector_type(4)));

union FragU { u32x4 u; bf16x8 b; };

// ---------- helpers ----------
__device__ inline unsigned int f2bf(float f){
  unsigned int u = __float_as_uint(f);
  return (u + 0x7fffu + ((u >> 16) & 1u)) >> 16;   // RNE to bf16
}
__device__ inline float bf2f(ushortT u){ return __uint_as_float(((unsigned)u) << 16); }
__device__ inline float gelu_f(float x){ return 0.5f * x * (1.f + erff(x * 0.70710678118f)); }

__device__ inline void gload16(const void* g, void* l){
  __builtin_amdgcn_global_load_lds(
      (const __attribute__((address_space(1))) void*)(uintptr_t)g,
      (__attribute__((address_space(3))) void*)(uintptr_t)l,
      16, 0, 0);
}

#define DSREAD(dst, addr, OFFS) \
  asm volatile("ds_read_b128 %0, %1 offset:" OFFS : "=v"(dst) : "v"(addr))

// ---------- weight conversion fp32 -> bf16 ----------
__global__ __launch_bounds__(256) void convw4_kernel(const float* __restrict__ s0,
    const float* __restrict__ s1, const float* __restrict__ s2, const float* __restrict__ s3,
    ushortT* __restrict__ dst)
{
  int idx = blockIdx.x * 256 + threadIdx.x;
  int e = idx * 8;
  if (e >= 7077888) return;
  const float* s; int loc;
  if (e < 1769472)      { s = s0; loc = e; }
  else if (e < 2359296) { s = s1; loc = e - 1769472; }
  else if (e < 4718592) { s = s2; loc = e - 2359296; }
  else                  { s = s3; loc = e - 4718592; }
  float4 a = *(const float4*)(s + loc);
  float4 c = *(const float4*)(s + loc + 4);
  uint4 o;
  o.x = f2bf(a.x) | (f2bf(a.y) << 16);
  o.y = f2bf(a.z) | (f2bf(a.w) << 16);
  o.z = f2bf(c.x) | (f2bf(c.y) << 16);
  o.w = f2bf(c.z) | (f2bf(c.w) << 16);
  *(uint4*)(dst + e) = o;
}

__global__ __launch_bounds__(256) void convw1_kernel(const float* __restrict__ s,
    ushortT* __restrict__ dst, int n8)
{
  int idx = blockIdx.x * 256 + threadIdx.x;
  if (idx >= n8) return;
  int e = idx * 8;
  float4 a = *(const float4*)(s + e);
  float4 c = *(const float4*)(s + e + 4);
  uint4 o;
  o.x = f2bf(a.x) | (f2bf(a.y) << 16);
  o.y = f2bf(a.z) | (f2bf(a.w) << 16);
  o.z = f2bf(c.x) | (f2bf(c.y) << 16);
  o.w = f2bf(c.z) | (f2bf(c.w) << 16);
  *(uint4*)(dst + e) = o;
}

// ---------- im2col (bf16 out) ----------
__global__ __launch_bounds__(256) void im2col_kernel(const float* __restrict__ x,
                                                     ushortT* __restrict__ out)
{
  int idx = blockIdx.x * 256 + threadIdx.x;
  const int tot = B_ * NPATCH * D_;
  if (idx >= tot) return;
  int m = idx / D_, k = idx - m * D_;
  int b = m / NPATCH, p = m - b * NPATCH;
  int pr = p / 14, pc = p - pr * 14;
  int c = k >> 8, r = k & 255;
  int py = r >> 4, px = r & 15;
  float v = x[(((size_t)(b * 3 + c) * 224) + pr * 16 + py) * 224 + pc * 16 + px];
  out[idx] = (ushortT)f2bf(v);
}

// ---------- fused assemble (cls/patch + pos -> h) + layer-0 LN1 (bf16 out) ----------
__global__ __launch_bounds__(256) void assemble_ln_kernel(const float* __restrict__ pe,
    const float* __restrict__ patch_b, const float* __restrict__ cls,
    const float* __restrict__ pos, float* __restrict__ h,
    const float* __restrict__ lw, const float* __restrict__ lb,
    ushortT* __restrict__ y)
{
  const int row = blockIdx.x;              // 0..ROWS-1
  const int b = row / NTOK, n = row - b * NTOK;
  const size_t base = (size_t)row * D_;
  const int t = threadIdx.x;
  float vals[3];
  float s = 0.f, ss = 0.f;
  #pragma unroll
  for (int e = 0; e < 3; e++) {
    int d = t + e * 256;
    float v;
    if (n == 0) v = cls[d];
    else        v = pe[((size_t)b * NPATCH + (n - 1)) * D_ + d] + patch_b[d];
    v += pos[(size_t)n * D_ + d];
    h[base + d] = v;
    vals[e] = v; s += v; ss += v * v;
  }
  #pragma unroll
  for (int off = 32; off >= 1; off >>= 1) {
    s  += __shfl_down(s, off);
    ss += __shfl_down(ss, off);
  }
  __shared__ float sm[4], ssm[4];
  int wid = t >> 6, lane = t & 63;
  if (lane == 0) { sm[wid] = s; ssm[wid] = ss; }
  __syncthreads();
  s  = sm[0] + sm[1] + sm[2] + sm[3];
  ss = ssm[0] + ssm[1] + ssm[2] + ssm[3];
  float mean = s * (1.f / D_);
  float var  = ss * (1.f / D_) - mean * mean;
  float inv  = rsqrtf(var + 1e-6f);
  #pragma unroll
  for (int e = 0; e < 3; e++) {
    int d = t + e * 256;
    y[base + d] = (ushortT)f2bf((vals[e] - mean) * inv * lw[d] + lb[d]);
  }
}

// ---------- fused split-K reduce (+bias) into h, optionally followed by LayerNorm ----------
template<int NP, int DOLN>
__global__ __launch_bounds__(256) void reduce_ln_kernel(
    const ushortT* __restrict__ p, const float* __restrict__ bias,
    float* __restrict__ h, const float* __restrict__ lw,
    const float* __restrict__ lb, ushortT* __restrict__ y)
{
  const size_t base = (size_t)blockIdx.x * D_;
  const int t = threadIdx.x;
  float vals[3];
  float s = 0.f, ss = 0.f;
  #pragma unroll
  for (int e = 0; e < 3; e++) {
    int d = t + e * 256;
    size_t idx = base + d;
    float acc = h[idx] + bias[d];
    #pragma unroll
    for (int q = 0; q < NP; q++) acc += bf2f(p[(size_t)q * PSZ + idx]);
    h[idx] = acc;
    vals[e] = acc; s += acc; ss += acc * acc;
  }
  if (DOLN) {
    #pragma unroll
    for (int off = 32; off >= 1; off >>= 1) {
      s  += __shfl_down(s, off);
      ss += __shfl_down(ss, off);
    }
    __shared__ float sm[4], ssm[4];
    int wid = t >> 6, lane = t & 63;
    if (lane == 0) { sm[wid] = s; ssm[wid] = ss; }
    __syncthreads();
    s  = sm[0] + sm[1] + sm[2] + sm[3];
    ss = ssm[0] + ssm[1] + ssm[2] + ssm[3];
    float mean = s * (1.f / D_);
    float var  = ss * (1.f / D_) - mean * mean;
    float inv  = rsqrtf(var + 1e-6f);
    #pragma unroll
    for (int e = 0; e < 3; e++) {
      int d = t + e * 256;
      y[base + d] = (ushortT)f2bf((vals[e] - mean) * inv * lw[d] + lb[d]);
    }
  }
}

// ---------- LayerNorm (one block per row), templated output ----------
template<int OUTBF>
__global__ __launch_bounds__(256) void ln_kernel(const float* __restrict__ x, size_t xstride,
    const float* __restrict__ w, const float* __restrict__ b,
    void* __restrict__ y, size_t ystride)
{
  const float* xr = x + (size_t)blockIdx.x * xstride;
  float vals[3];
  float s = 0.f, ss = 0.f;
  #pragma unroll
  for (int t = 0; t < 3; t++) {
    float v = xr[threadIdx.x + t * 256];
    vals[t] = v; s += v; ss += v * v;
  }
  #pragma unroll
  for (int off = 32; off >= 1; off >>= 1) {
    s  += __shfl_down(s, off);
    ss += __shfl_down(ss, off);
  }
  __shared__ float sm[4], ssm[4];
  int wid = threadIdx.x >> 6, lane = threadIdx.x & 63;
  if (lane == 0) { sm[wid] = s; ssm[wid] = ss; }
  __syncthreads();
  s  = sm[0] + sm[1] + sm[2] + sm[3];
  ss = ssm[0] + ssm[1] + ssm[2] + ssm[3];
  float mean = s * (1.f / D_);
  float var  = ss * (1.f / D_) - mean * mean;
  float inv  = rsqrtf(var + 1e-6f);
  #pragma unroll
  for (int t = 0; t < 3; t++) {
    int d = threadIdx.x + t * 256;
    float v = (vals[t] - mean) * inv * w[d] + b[d];
    if (OUTBF) ((ushortT*)y)[(size_t)blockIdx.x * ystride + d] = (ushortT)f2bf(v);
    else       ((float*)y)  [(size_t)blockIdx.x * ystride + d] = v;
  }
}

// ---------- high-occupancy bf16 MFMA GEMM: 128x64 tile, wave=64x32, 6 blocks/CU ----------
// acc 4x2 (32 AGPR); LDS 24KB (A [2][4096] @0, W [2][2048] @ elem 8192);
// 3 staging loads/wave/tile, counted vmcnt(3) depth-2 pipeline.
// Swizzle: source col chunk (L&3)^((L>>3)&3) pre-swizzle; read slot kc^((rsel>>1)&3).
template<int OUTBF, int ACT, int HASRES>
__global__ __launch_bounds__(256, 6) void gemm_mfma(
    const ushortT* __restrict__ A, const ushortT* __restrict__ W,
    const float* __restrict__ bias, const float* __restrict__ resid,
    void* __restrict__ Cout, int M, int N, int K, int LDA, int LDW)
{
  __shared__ ushortT lds[12288];   // 24 KB
  const int tid = threadIdx.x, lane = tid & 63, wid = tid >> 6;
  const int bm = blockIdx.y * 128, bn = blockIdx.x * 64;
  const int wm = (wid >> 1) * 64, wn = (wid & 1) * 32;
  const int kz = blockIdx.z;
  A += (size_t)kz * K; W += (size_t)kz * K;
  char* Cb = (char*)Cout + (size_t)kz * M * N * (OUTBF ? 2 : 4);

  const int srow = lane >> 2;
  const int scol = ((lane & 3) ^ ((lane >> 3) & 3)) * 8;
  int arow0 = bm + (2 * wid) * 16 + srow;     if (arow0 > M - 1) arow0 = M - 1;
  int arow1 = bm + (2 * wid + 1) * 16 + srow; if (arow1 > M - 1) arow1 = M - 1;
  const int wrow = bn + wid * 16 + srow;
  const ushortT* aP0 = A + (size_t)arow0 * LDA + scol;
  const ushortT* aP1 = A + (size_t)arow1 * LDA + scol;
  const ushortT* wP0 = W + (size_t)wrow * LDW + scol;
  ushortT* sA = lds + 2 * wid * 512;
  ushortT* sW = lds + 8192 + wid * 512;

  f32x4 acc[4][2];
  #pragma unroll
  for (int i = 0; i < 4; i++)
    #pragma unroll
    for (int j = 0; j < 2; j++)
      acc[i][j] = (f32x4){0.f, 0.f, 0.f, 0.f};

  const int rsel = lane & 15, kc = lane >> 4;
  const unsigned ldsbase = (unsigned)(size_t)&lds[0];
  const unsigned rowoff = (unsigned)(rsel * 64 + ((kc ^ ((rsel >> 1) & 3)) << 4));
  const unsigned aBase = ldsbase + (unsigned)(wm * 64) + rowoff;
  const unsigned bBase = ldsbase + 16384u + (unsigned)(wn * 64) + rowoff;

  const int nk = K >> 5;

  #pragma unroll
  for (int p = 0; p < 2; ++p) {
    const int off = p * 32;
    gload16(aP0 + off, sA + p * 4096); gload16(aP1 + off, sA + p * 4096 + 512);
    gload16(wP0 + off, sW + p * 2048);
  }

  for (int kt = 0; kt < nk; ++kt) {
    const int cb = kt & 1;
    asm volatile("s_waitcnt vmcnt(3)" ::: "memory");
    __builtin_amdgcn_sched_barrier(0);
    __builtin_amdgcn_s_barrier();

    const unsigned aAddr = aBase + (unsigned)cb * 8192u;
    const unsigned bAddr = bBase + (unsigned)cb * 4096u;
    FragU fa0, fa1, fa2, fa3, fb0, fb1;
    DSREAD(fa0.u, aAddr, "0");
    DSREAD(fa1.u, aAddr, "1024");
    DSREAD(fa2.u, aAddr, "2048");
    DSREAD(fa3.u, aAddr, "3072");
    DSREAD(fb0.u, bAddr, "0");
    DSREAD(fb1.u, bAddr, "1024");
    asm volatile("s_waitcnt lgkmcnt(0)" ::: "memory");
    __builtin_amdgcn_sched_barrier(0);
    __builtin_amdgcn_s_barrier();

    const int nt = kt + 2;
    const int off = (nt < nk) ? nt * 32 : 0;
    gload16(aP0 + off, sA + cb * 4096); gload16(aP1 + off, sA + cb * 4096 + 512);
    gload16(wP0 + off, sW + cb * 2048);

    acc[0][0] = __builtin_amdgcn_mfma_f32_16x16x32_bf16(fa0.b, fb0.b, acc[0][0], 0, 0, 0);
    acc[0][1] = __builtin_amdgcn_mfma_f32_16x16x32_bf16(fa0.b, fb1.b, acc[0][1], 0, 0, 0);
    acc[1][0] = __builtin_amdgcn_mfma_f32_16x16x32_bf16(fa1.b, fb0.b, acc[1][0], 0, 0, 0);
    acc[1][1] = __builtin_amdgcn_mfma_f32_16x16x32_bf16(fa1.b, fb1.b, acc[1][1], 0, 0, 0);
    acc[2][0] = __builtin_amdgcn_mfma_f32_16x16x32_bf16(fa2.b, fb0.b, acc[2][0], 0, 0, 0);
    acc[2][1] = __builtin_amdgcn_mfma_f32_16x16x32_bf16(fa2.b, fb1.b, acc[2][1], 0, 0, 0);
    acc[3][0] = __builtin_amdgcn_mfma_f32_16x16x32_bf16(fa3.b, fb0.b, acc[3][0], 0, 0, 0);
    acc[3][1] = __builtin_amdgcn_mfma_f32_16x16x32_bf16(fa3.b, fb1.b, acc[3][1], 0, 0, 0);
  }

  const int crow = (lane >> 4) * 4, ccol = lane & 15;
  #pragma unroll
  for (int i = 0; i < 4; i++) {
    #pragma unroll
    for (int r = 0; r < 4; r++) {
      int m = bm + wm + i * 16 + crow + r;
      if (m < M) {
        #pragma unroll
        for (int j = 0; j < 2; j++) {
          int n = bn + wn + j * 16 + ccol;
          float v = acc[i][j][r];
          if (bias) v += bias[n];
          if (ACT) v = gelu_f(v);
          if (HASRES) v += resid[(size_t)m * N + n];
          if (OUTBF) ((ushortT*)Cb)[(size_t)m * N + n] = (ushortT)f2bf(v);
          else       ((float*)Cb)  [(size_t)m * N + n] = v;
        }
      }
    }
  }
  asm volatile("s_waitcnt vmcnt(0)" ::: "memory");
}

// ---------- MFMA attention (unchanged) ----------
#define KROWS 208
#define VSTR  232
__global__ __launch_bounds__(256) void attn_mfma(
    const ushortT* __restrict__ qkv, const float* __restrict__ prefix_k,
    const float* __restrict__ prefix_v, const float* __restrict__ act_scale,
    const int* __restrict__ task_id, ushortT* __restrict__ out,
    int layer, int koff)
{
  __shared__ ushortT smem[13312 + 14848 + 4096];   // 64512 B
  ushortT* Kl = smem;
  ushortT* Vt = smem + 13312;
  ushortT* Ps = smem + 13312 + 14848;

  const int tid = threadIdx.x, lane = tid & 63, wid = tid >> 6;
  const int g = lane >> 4, qc = lane & 15;
  const int qh = blockIdx.x, h = blockIdx.y, b = blockIdx.z;
  const int KtA = NTOK + koff;

  int tsk = 0;
  float s0 = 1.f, s1 = 1.f;
  if (koff) {
    tsk = task_id[b]; tsk = tsk < 0 ? 0 : (tsk > TASKS_ - 1 ? TASKS_ - 1 : tsk);
    s0 = act_scale[layer * 2]; s1 = act_scale[layer * 2 + 1];
  }

  {
    uint4* vz = (uint4*)Vt;
    for (int i = tid; i < 14848 / 8; i += 256) vz[i] = (uint4){0, 0, 0, 0};
    uint4* kz = (uint4*)(Kl + 202 * 64);
    if (tid < 48) kz[tid] = (uint4){0, 0, 0, 0};
  }
  __syncthreads();

  for (int u = tid; u < KtA * 8; u += 256) {
    int row = u >> 3, cg = u & 7;
    uint4 val;
    if (row < koff) {
      size_t off = ((((size_t)layer * TASKS_ + tsk) * PL_ + row) * H_ + h) * HD_ + cg * 8;
      float4 f0 = *(const float4*)(prefix_k + off);
      float4 f1 = *(const float4*)(prefix_k + off + 4);
      val.x = f2bf(f0.x) | (f2bf(f0.y) << 16); val.y = f2bf(f0.z) | (f2bf(f0.w) << 16);
      val.z = f2bf(f1.x) | (f2bf(f1.y) << 16); val.w = f2bf(f1.z) | (f2bf(f1.w) << 16);
    } else {
      int n = row - koff;
      val = *(const uint4*)(qkv + ((size_t)b * NTOK + n) * 2304 + D_ + h * HD_ + cg * 8);
    }
    *(uint4*)(Kl + row * 64 + ((cg * 8) ^ ((row & 7) << 3))) = val;
  }
  for (int u = tid; u < KtA * 8; u += 256) {
    int row = u >> 3, dg = u & 7;
    ushortT e[8];
    if (row < koff) {
      size_t off = ((((size_t)layer * TASKS_ + tsk) * PL_ + row) * H_ + h) * HD_ + dg * 8;
      #pragma unroll
      for (int t = 0; t < 8; t++) e[t] = (ushortT)f2bf(prefix_v[off + t]);
    } else {
      int n = row - koff;
      uint4 v = *(const uint4*)(qkv + ((size_t)b * NTOK + n) * 2304 + 2 * D_ + h * HD_ + dg * 8);
      *(uint4*)e = v;
    }
    #pragma unroll
    for (int t = 0; t < 8; t++) Vt[(dg * 8 + t) * VSTR + row] = e[t];
  }
  __syncthreads();

  const int tend = qh ? 13 : 7;
  for (int t = qh * 7 + wid; t < tend; t += 4) {
    const int q0 = t * 16;
    int qr = q0 + qc; if (qr > NTOK - 1) qr = NTOK - 1;
    const ushortT* qp = qkv + ((size_t)b * NTOK + qr) * 2304 + h * HD_ + g * 8;
    bf16x8 qf0 = *(const bf16x8*)qp;
    bf16x8 qf1 = *(const bf16x8*)(qp + 32);

    f32x4 sacc[13];
    #pragma unroll
    for (int kt = 0; kt < 13; kt++) sacc[kt] = (f32x4){0.f, 0.f, 0.f, 0.f};
    #pragma unroll
    for (int kt = 0; kt < 13; kt++) {
      int row = kt * 16 + qc;
      int sw = (row & 7) << 3;
      bf16x8 ka0 = *(const bf16x8*)(Kl + row * 64 + ((g * 8) ^ sw));
      bf16x8 ka1 = *(const bf16x8*)(Kl + row * 64 + ((32 + g * 8) ^ sw));
      sacc[kt] = __builtin_amdgcn_mfma_f32_16x16x32_bf16(ka0, qf0, sacc[kt], 0, 0, 0);
      sacc[kt] = __builtin_amdgcn_mfma_f32_16x16x32_bf16(ka1, qf1, sacc[kt], 0, 0, 0);
    }

    float* sp = (float*)sacc;
    float mx = -1e30f;
    #pragma unroll
    for (int kt = 0; kt < 13; kt++)
      #pragma unroll
      for (int r = 0; r < 4; r++) {
        int k = kt * 16 + g * 4 + r;
        float s = sp[kt * 4 + r] * SCALE_;
        if (koff && k < PL_) s += s1 / (1.f + __expf(-s * s0));
        if (k >= KtA) s = -1e30f;
        sp[kt * 4 + r] = s;
        mx = fmaxf(mx, s);
      }
    mx = fmaxf(mx, __shfl_xor(mx, 16));
    mx = fmaxf(mx, __shfl_xor(mx, 32));
    float sum = 0.f;
    #pragma unroll
    for (int i = 0; i < 52; i++) { float p = __expf(sp[i] - mx); sp[i] = p; sum += p; }
    sum += __shfl_xor(sum, 16);
    sum += __shfl_xor(sum, 32);
    const float inv = 1.f / sum;

    f32x4 oacc[4];
    #pragma unroll
    for (int d = 0; d < 4; d++) oacc[d] = (f32x4){0.f, 0.f, 0.f, 0.f};
    #pragma unroll
    for (int c = 0; c < 7; c++) {
      ushortT* slab = Ps + wid * 1024 + (c & 1) * 512;
      uint2 w0, w1;
      {
        float p0 = sp[8 * c + 0] * inv, p1 = sp[8 * c + 1] * inv;
        float p2 = sp[8 * c + 2] * inv, p3 = sp[8 * c + 3] * inv;
        w0.x = f2bf(p0) | (f2bf(p1) << 16); w0.y = f2bf(p2) | (f2bf(p3) << 16);
      }
      if (c < 6) {
        float p0 = sp[8 * c + 4] * inv, p1 = sp[8 * c + 5] * inv;
        float p2 = sp[8 * c + 6] * inv, p3 = sp[8 * c + 7] * inv;
        w1.x = f2bf(p0) | (f2bf(p1) << 16); w1.y = f2bf(p2) | (f2bf(p3) << 16);
      } else { w1.x = 0; w1.y = 0; }
      *(uint2*)(slab + qc * 32 + g * 4) = w0;
      *(uint2*)(slab + qc * 32 + 16 + g * 4) = w1;
      bf16x8 pa = *(const bf16x8*)(slab + qc * 32 + g * 8);
      #pragma unroll
      for (int dt = 0; dt < 4; dt++) {
        bf16x8 vb = *(const bf16x8*)(Vt + (dt * 16 + qc) * VSTR + c * 32 + g * 8);
        oacc[dt] = __builtin_amdgcn_mfma_f32_16x16x32_bf16(pa, vb, oacc[dt], 0, 0, 0);
      }
    }

    #pragma unroll
    for (int r = 0; r < 4; r++) {
      int q = q0 + g * 4 + r;
      if (q < NTOK) {
        size_t ro = ((size_t)b * NTOK + q) * D_ + h * HD_;
        #pragma unroll
        for (int dt = 0; dt < 4; dt++)
          out[ro + dt * 16 + qc] = (ushortT)f2bf(oacc[dt][r]);
      }
    }
  }
}

// ---------- launch ----------
extern "C" void kernel_launch(void* const* d_in, const int* in_sizes, int n_in,
                              void* d_out, int out_size, void* d_ws, size_t ws_size,
                              hipStream_t stream)
{
  (void)in_sizes; (void)n_in; (void)out_size; (void)ws_size;
  const float* x         = (const float*)d_in[0];
  const int*   task_id   = (const int*)  d_in[1];
  const float* patch_w   = (const float*)d_in[2];
  const float* patch_b   = (const float*)d_in[3];
  const float* cls_token = (const float*)d_in[4];
  const float* pos_embed = (const float*)d_in[5];
  const float* ln1_w     = (const float*)d_in[6];
  const float* ln1_b     = (const float*)d_in[7];
  const float* qkv_w     = (const float*)d_in[8];
  const float* qkv_b     = (const float*)d_in[9];
  const float* proj_w    = (const float*)d_in[10];
  const float* proj_b    = (const float*)d_in[11];
  const float* ln2_w     = (const float*)d_in[12];
  const float* ln2_b     = (const float*)d_in[13];
  const float* fc1_w     = (const float*)d_in[14];
  const float* fc1_b     = (const float*)d_in[15];
  const float* fc2_w     = (const float*)d_in[16];
  const float* fc2_b     = (const float*)d_in[17];
  const float* norm_w    = (const float*)d_in[18];
  const float* norm_b    = (const float*)d_in[19];
  const float* prefix_k  = (const float*)d_in[20];
  const float* prefix_v  = (const float*)d_in[21];
  const float* act_scale = (const float*)d_in[22];
  float* out = (float*)d_out;

  char* wsb = (char*)d_ws;
  float*   h      = (float*)  (wsb);
  ushortT* actA   = (ushortT*)(wsb + 19365888);
  ushortT* qkvbuf = (ushortT*)(wsb + 29048832);   // also split-K partials
  ushortT* mlpbuf = (ushortT*)(wsb + 58097664);
  ushortT* wsc    = (ushortT*)(wsb + 96829440);
  float*   peout  = (float*)qkvbuf;

  ushortT* wqkv  = wsc;
  ushortT* wproj = wsc + 1769472;
  ushortT* wfc1  = wsc + 2359296;
  ushortT* wfc2  = wsc + 4718592;

  // ---- patch embedding ----
  convw1_kernel<<<288, 256, 0, stream>>>(patch_w, wsc, 73728);
  im2col_kernel<<<(B_ * NPATCH * D_ + 255) / 256, 256, 0, stream>>>(x, actA);
  gemm_mfma<0,0,0><<<dim3(12, 49), 256, 0, stream>>>(
      actA, wsc, nullptr, nullptr, peout, B_ * NPATCH, D_, D_, D_, D_);
  // fused assemble + layer-0 ln1
  assemble_ln_kernel<<<ROWS, 256, 0, stream>>>(
      peout, patch_b, cls_token, pos_embed, h, ln1_w, ln1_b, actA);

  // ---- transformer layers ----
  for (int i = 0; i < DEPTH_; i++) {
    convw4_kernel<<<3456, 256, 0, stream>>>(
        qkv_w + (size_t)i * 1769472, proj_w + (size_t)i * 589824,
        fc1_w + (size_t)i * 2359296, fc2_w + (size_t)i * 2359296, wsc);
    gemm_mfma<1,0,0><<<dim3(36, 50), 256, 0, stream>>>(
        actA, wqkv, qkv_b + i * 3 * D_, nullptr, qkvbuf, ROWS, 3 * D_, D_, D_, D_);
    attn_mfma<<<dim3(2, H_, B_), 256, 0, stream>>>(
        qkvbuf, prefix_k, prefix_v, act_scale, task_id, actA, i, (i < NPL_) ? PL_ : 0);
    // proj split-K x2: bf16 partials -> qkvbuf
    gemm_mfma<1,0,0><<<dim3(12, 50, 2), 256, 0, stream>>>(
        actA, wproj, nullptr, nullptr, qkvbuf, ROWS, D_, D_ / 2, D_, D_);
    reduce_ln_kernel<2,1><<<ROWS, 256, 0, stream>>>(
        qkvbuf, proj_b + i * D_, h, ln2_w + i * D_, ln2_b + i * D_, actA);
    gemm_mfma<1,1,0><<<dim3(48, 50), 256, 0, stream>>>(
        actA, wfc1, fc1_b + i * MLPD_, nullptr, mlpbuf, ROWS, MLPD_, D_, D_, D_);
    // fc2 split-K x3: bf16 partials -> qkvbuf
    gemm_mfma<1,0,0><<<dim3(12, 50, 3), 256, 0, stream>>>(
        mlpbuf, wfc2, nullptr, nullptr, qkvbuf, ROWS, D_, MLPD_ / 3, MLPD_, MLPD_);
    if (i < DEPTH_ - 1) {
      reduce_ln_kernel<3,1><<<ROWS, 256, 0, stream>>>(
          qkvbuf, fc2_b + i * D_, h, ln1_w + (i + 1) * D_, ln1_b + (i + 1) * D_, actA);
    } else {
      reduce_ln_kernel<3,0><<<ROWS, 256, 0, stream>>>(
          qkvbuf, fc2_b + i * D_, h, nullptr, nullptr, nullptr);
    }
  }

  // ---- final LN on token 0 only ----
  ln_kernel<0><<<B_, 256, 0, stream>>>(h, (size_t)NTOK * D_, norm_w, norm_b, out, D_);
}